// Round 2
// baseline (345.720 us; speedup 1.0000x reference)
//
#include <hip/hip_runtime.h>

// Problem constants (fixed by setup_inputs)
constexpr int kB = 256;      // batch
constexpr int kN = 128;      // seq len
constexpr int kM = 512;      // mem width
constexpr int kSlots = 15;   // his_mem slots
constexpr int kS = 16;       // slots incl. null
constexpr int kW = 1536;     // attn_W row length (d_q + M)
constexpr int kMsStride = 520;  // mem staging stride (banks: +8 per row, CF)
constexpr int kCsStride = 528;  // C stride (2-way aliasing only -> free)

__device__ __forceinline__ float tanh_fast(float x)
{
    float xc = fminf(15.f, fmaxf(-15.f, x));
    float ex = __expf(2.f * xc);
    return 1.f - 2.f * __builtin_amdgcn_rcpf(ex + 1.f);
}

// ---------------------------------------------------------------------------
// One kernel, one block per batch, ZERO inter-block communication.
// Per block b:
//   A) fused: empty flags + hm->out copy + Ms (mem) LDS staging; gumbel
//      ambiguity filter + ballot-scan ordered step list; default log rows.
//      cnt==0 (~78% of batches) -> done (~4us).
//   B) C0 GEMM (16x512x512) into LDS Cs: W row-slice in registers, reused
//      across all 16 slots; next-chunk prefetch. ~14-16us (VALU floor/CU).
//   C) serial walk over flagged steps: q-GEMV on demand -> Qs LDS, e-eval
//      (tanh), softmax+gumbel+argmax, log one-hot; on write: cw-GEMV into
//      Cs row + empty update. ~3-4us/step, cnt is 1-3 for real inputs.
//   D) epilogue: overwrite written hm slots from states.
// ---------------------------------------------------------------------------
__global__ __launch_bounds__(256) void fused_k(
    const float* __restrict__ his_mem, const float* __restrict__ states,
    const float* __restrict__ states_mask, const float* __restrict__ global_trace,
    const float* __restrict__ null_mem, const float* __restrict__ gumbel_u,
    const float* __restrict__ W, const float* __restrict__ attn_b,
    const float* __restrict__ v, float* __restrict__ out)
{
    const int b = blockIdx.x;
    const int tid = threadIdx.x;
    const int wave = tid >> 6, lane = tid & 63;

    __shared__ __align__(16) float Ms[kS * kMsStride];   // mem rows
    __shared__ __align__(16) float Cs[kS * kCsStride];   // C (evolving)
    __shared__ __align__(16) float Xq[1024];             // [state | gt]
    __shared__ __align__(16) float Qs[kM];               // q for current step
    __shared__ __align__(16) float vs[kM];               // v
    __shared__ __align__(16) float bs[kM];               // attn_b
    __shared__ float empty_p[kS];
    __shared__ float e_sh[kS];
    __shared__ unsigned char ambList[kN];
    __shared__ int wcnt[2];
    __shared__ int slot_src[kSlots];
    __shared__ int cnt_sh, k_sh, wk_sh, nz_sh;

    float* out_hm = out;
    float* out_log = out + (size_t)kB * kSlots * kM;

    // ======================= phase A =======================
    for (int s = wave; s < kS; s += 4) {
        const float* p = (s < kSlots) ? his_mem + ((size_t)b * kSlots + s) * kM
                                      : null_mem + (size_t)b * kM;
        float4 v0 = *(const float4*)(p + lane * 4);
        float4 v1 = *(const float4*)(p + 256 + lane * 4);
        *(float4*)&Ms[s * kMsStride + lane * 4] = v0;
        *(float4*)&Ms[s * kMsStride + 256 + lane * 4] = v1;
        int nz = (v0.x != 0.f) | (v0.y != 0.f) | (v0.z != 0.f) | (v0.w != 0.f) |
                 (v1.x != 0.f) | (v1.y != 0.f) | (v1.z != 0.f) | (v1.w != 0.f);
        unsigned long long bal = __ballot(nz);
        if (lane == 0) empty_p[s] = (bal == 0ull) ? 1.f : 0.f;
        if (s < kSlots) {
            float* dst = out_hm + ((size_t)b * kSlots + s) * kM;
            *(float4*)(dst + lane * 4) = v0;
            *(float4*)(dst + 256 + lane * 4) = v1;
        }
    }
    __syncthreads();

    bool amb = false;
    if (tid < kN) {
        const int idx = b * kN + tid;
        const float* up = gumbel_u + (size_t)idx * kS;
        float g[kS];
#pragma unroll
        for (int s = 0; s < kS; ++s) {
            float u = fminf(fmaxf(up[s], 1e-20f), 1.0f);
            g[s] = -logf(-logf(u) + 1e-20f);
        }
        float rhs = g[15] + 10.f * empty_p[15] - 1.01f;
#pragma unroll
        for (int s = 0; s < kSlots; ++s)
            amb = amb || (g[s] + 10.f * empty_p[s] >= rhs);
        // default one-hot(15) log row (walk overwrites flagged steps later)
        float* lp = out_log + (size_t)idx * kS;
        float4 zz = make_float4(0.f, 0.f, 0.f, 0.f);
        *(float4*)(lp + 0) = zz;
        *(float4*)(lp + 4) = zz;
        *(float4*)(lp + 8) = zz;
        *(float4*)(lp + 12) = make_float4(0.f, 0.f, 0.f, 1.f);
    }
    unsigned long long m = __ballot(amb);
    if (tid < kN && (tid & 63) == 0) wcnt[tid >> 6] = __popcll(m);
    __syncthreads();
    if (tid < kN && amb) {
        int base = (tid >= 64) ? wcnt[0] : 0;
        int pos = base + __popcll(m & ((1ull << (tid & 63)) - 1ull));
        ambList[pos] = (unsigned char)tid;   // ascending step order
    }
    if (tid == 0) cnt_sh = wcnt[0] + wcnt[1];
    if (tid < kSlots) slot_src[tid] = -1;
    __syncthreads();
    const int cnt = cnt_sh;
    if (cnt == 0) return;                    // defaults already correct

    // stage v, attn_b, global_trace (constant per batch)
    for (int i = tid; i < kM; i += 256) {
        vs[i] = v[i];
        bs[i] = attn_b[i];
        Xq[512 + i] = global_trace[(size_t)b * kM + i];
    }

    // ======================= phase B: C0 GEMM -> Cs =======================
    // C0[s][r] = sum_k W[r][1024+k] * Ms[s][k]
    // thread (g = tid>>4, l = tid&15): row r = r0+g, k-slice l*4 + 64*jj.
    // W slice lives in 8 float4 registers, reused across all 16 slots.
    {
        const int g = tid >> 4, l = tid & 15;
        const int koff = l * 4;
        float4 w4[8];
        {
            const float* wr = W + (size_t)g * kW + 1024;
#pragma unroll
            for (int jj = 0; jj < 8; ++jj)
                w4[jj] = *(const float4*)(wr + koff + jj * 64);
        }
        for (int r0 = 0; r0 < kM; r0 += 16) {
            float4 wn[8];
            if (r0 + 16 < kM) {
                const float* wr = W + (size_t)(r0 + 16 + g) * kW + 1024;
#pragma unroll
                for (int jj = 0; jj < 8; ++jj)
                    wn[jj] = *(const float4*)(wr + koff + jj * 64);
            }
            const int r = r0 + g;
#pragma unroll
            for (int s = 0; s < kS; ++s) {
                const float* ms = &Ms[s * kMsStride + koff];
                float a0 = 0.f, a1 = 0.f, a2 = 0.f, a3 = 0.f;
#pragma unroll
                for (int jj = 0; jj < 8; ++jj) {
                    float4 m4 = *(const float4*)(ms + jj * 64);
                    a0 = fmaf(w4[jj].x, m4.x, a0);
                    a1 = fmaf(w4[jj].y, m4.y, a1);
                    a2 = fmaf(w4[jj].z, m4.z, a2);
                    a3 = fmaf(w4[jj].w, m4.w, a3);
                }
                float a = (a0 + a1) + (a2 + a3);
                a += __shfl_xor(a, 1); a += __shfl_xor(a, 2);
                a += __shfl_xor(a, 4); a += __shfl_xor(a, 8);
                if (l == s) Cs[s * kCsStride + r] = a;   // lane s stores slot s
            }
#pragma unroll
            for (int jj = 0; jj < 8; ++jj) w4[jj] = wn[jj];
        }
    }
    __syncthreads();

    // ======================= phase C: serial walk =======================
    const int sidx = tid >> 4;   // e-eval: slot per 16-lane group
    const int ml = tid & 15;
    const int g = tid >> 4, l = tid & 15;
    const int koff = l * 4;

    for (int jj = 0; jj < cnt; ++jj) {
        const int t = ambList[jj];
        const int idx = b * kN + t;

        // stage state, detect nonzero
        if (tid == 0) nz_sh = 0;
        __syncthreads();
        {
            float s0 = states[(size_t)idx * kM + tid];
            float s1 = states[(size_t)idx * kM + 256 + tid];
            Xq[tid] = s0; Xq[256 + tid] = s1;
            if (s0 != 0.f || s1 != 0.f) nz_sh = 1;
        }
        __syncthreads();

        // q-GEMV: Qs[r] = bs[r] + sum_{k<1024} W[r][k] * Xq[k]
#pragma unroll 2
        for (int r0 = 0; r0 < kM; r0 += 16) {
            const int r = r0 + g;
            const float* wr = W + (size_t)r * kW;
            float a0 = 0.f, a1 = 0.f, a2 = 0.f, a3 = 0.f;
#pragma unroll
            for (int q = 0; q < 16; ++q) {
                float4 wv = *(const float4*)(wr + koff + q * 64);
                float4 xv = *(const float4*)&Xq[koff + q * 64];
                a0 = fmaf(wv.x, xv.x, a0); a1 = fmaf(wv.y, xv.y, a1);
                a2 = fmaf(wv.z, xv.z, a2); a3 = fmaf(wv.w, xv.w, a3);
            }
            float a = (a0 + a1) + (a2 + a3);
            a += __shfl_xor(a, 1); a += __shfl_xor(a, 2);
            a += __shfl_xor(a, 4); a += __shfl_xor(a, 8);
            if (l == 0) Qs[r] = a + bs[r];
        }
        __syncthreads();

        // e[s] = sum_m v[m] * tanh(Qs[m] + Cs[s][m])
        {
            const float* crow = &Cs[sidx * kCsStride];
            float acc = 0.f;
#pragma unroll
            for (int j = 0; j < 8; ++j) {
                int mcol = ml * 4 + j * 64;
                float4 q4 = *(const float4*)&Qs[mcol];
                float4 c4 = *(const float4*)&crow[mcol];
                float4 v4 = *(const float4*)&vs[mcol];
                acc = fmaf(v4.x, tanh_fast(q4.x + c4.x), acc);
                acc = fmaf(v4.y, tanh_fast(q4.y + c4.y), acc);
                acc = fmaf(v4.z, tanh_fast(q4.z + c4.z), acc);
                acc = fmaf(v4.w, tanh_fast(q4.w + c4.w), acc);
            }
            acc += __shfl_xor(acc, 1); acc += __shfl_xor(acc, 2);
            acc += __shfl_xor(acc, 4); acc += __shfl_xor(acc, 8);
            if (ml == 0) e_sh[sidx] = acc;
        }
        __syncthreads();

        // wave 0: softmax + empty mask + gumbel + first-max argmax
        if (tid < 64) {
            int s = tid;
            float ev = (s < kS) ? e_sh[s] : -3.0e38f;
            float mx = ev;
            mx = fmaxf(mx, __shfl_xor(mx, 1));
            mx = fmaxf(mx, __shfl_xor(mx, 2));
            mx = fmaxf(mx, __shfl_xor(mx, 4));
            mx = fmaxf(mx, __shfl_xor(mx, 8));
            float w = (s < kS) ? __expf(ev - mx) : 0.f;
            float sm = w;
            sm += __shfl_xor(sm, 1); sm += __shfl_xor(sm, 2);
            sm += __shfl_xor(sm, 4); sm += __shfl_xor(sm, 8);
            w = w / sm;
            w += 10.0f * ((s < kS) ? empty_p[s] : 0.f);
            float z;
            if (s < kS) {
                float u = gumbel_u[(size_t)idx * kS + s];
                u = fminf(fmaxf(u, 1e-20f), 1.0f);
                float gn = -logf(-logf(u) + 1e-20f);
                z = w + gn;           // tau = 1.0
            } else z = -3.0e38f;
            float zm = z;
            zm = fmaxf(zm, __shfl_xor(zm, 1));
            zm = fmaxf(zm, __shfl_xor(zm, 2));
            zm = fmaxf(zm, __shfl_xor(zm, 4));
            zm = fmaxf(zm, __shfl_xor(zm, 8));
            unsigned long long bal = __ballot(z == zm) & 0xFFFFull;
            if (s == 0) k_sh = __ffsll(bal) - 1;   // first-max (jnp.argmax)
        }
        __syncthreads();

        const int k = k_sh;
        if (tid < kS)
            out_log[(size_t)idx * kS + tid] = (tid == k) ? 1.f : 0.f;
        if (tid == 0) {
            float mv = states_mask[idx];
            wk_sh = (k < kSlots && mv != 0.0f) ? k : -1;
        }
        __syncthreads();

        const int wk = wk_sh;
        if (wk >= 0) {
            // cw-GEMV into Cs[wk]: sum_{k<512} W[r][1024+k] * state[k]
            for (int r0 = 0; r0 < kM; r0 += 16) {
                const int r = r0 + g;
                const float* wr = W + (size_t)r * kW + 1024;
                float a0 = 0.f, a1 = 0.f, a2 = 0.f, a3 = 0.f;
#pragma unroll
                for (int q = 0; q < 8; ++q) {
                    float4 wv = *(const float4*)(wr + koff + q * 64);
                    float4 xv = *(const float4*)&Xq[koff + q * 64];
                    a0 = fmaf(wv.x, xv.x, a0); a1 = fmaf(wv.y, xv.y, a1);
                    a2 = fmaf(wv.z, xv.z, a2); a3 = fmaf(wv.w, xv.w, a3);
                }
                float a = (a0 + a1) + (a2 + a3);
                a += __shfl_xor(a, 1); a += __shfl_xor(a, 2);
                a += __shfl_xor(a, 4); a += __shfl_xor(a, 8);
                if (l == 0) Cs[wk * kCsStride + r] = a;
            }
            if (tid == 0) {
                slot_src[wk] = t;
                empty_p[wk] = nz_sh ? 0.f : 1.f;
            }
        }
        __syncthreads();
    }

    // ======================= phase D: epilogue =======================
    for (int s = 0; s < kSlots; ++s) {
        int ts = slot_src[s];
        if (ts >= 0) {
            float* dst = out_hm + ((size_t)b * kSlots + s) * kM;
            dst[tid] = states[((size_t)b * kN + ts) * kM + tid];
            dst[tid + 256] = states[((size_t)b * kN + ts) * kM + tid + 256];
        }
    }
}

// ---------------------------------------------------------------------------
extern "C" void kernel_launch(void* const* d_in, const int* in_sizes, int n_in,
                              void* d_out, int out_size, void* d_ws, size_t ws_size,
                              hipStream_t stream)
{
    const float* his_mem      = (const float*)d_in[0];
    const float* states       = (const float*)d_in[1];
    const float* states_mask  = (const float*)d_in[2];
    const float* global_trace = (const float*)d_in[3];
    const float* null_mem     = (const float*)d_in[4];
    const float* gumbel_u     = (const float*)d_in[5];
    const float* attn_W       = (const float*)d_in[6];
    const float* attn_b       = (const float*)d_in[7];
    const float* v            = (const float*)d_in[8];

    // No workspace, no memset, no barriers: one launch, one block per batch.
    fused_k<<<kB, 256, 0, stream>>>(his_mem, states, states_mask, global_trace,
                                    null_mem, gumbel_u, attn_W, attn_b, v,
                                    (float*)d_out);
}

// Round 3
// 256.191 us; speedup vs baseline: 1.3495x; 1.3495x over previous
//
#include <hip/hip_runtime.h>

// Problem constants (fixed by setup_inputs)
constexpr int kB = 256;      // batch
constexpr int kN = 128;      // seq len
constexpr int kM = 512;      // mem width
constexpr int kSlots = 15;   // his_mem slots
constexpr int kS = 16;       // slots incl. null
constexpr int kW = 1536;     // attn_W row length (d_q + M)
constexpr int kQC = 16;      // cached steps per batch (cnt>16 -> inline fallback)
constexpr int kCsStride = 528;  // walk C stride (2-way bank aliasing = free)

__device__ __forceinline__ float tanh_fast(float x)
{
    float xc = fminf(15.f, fmaxf(-15.f, x));
    float ex = __expf(2.f * xc);
    return 1.f - 2.f * __builtin_amdgcn_rcpf(ex + 1.f);
}

// ---------------------------------------------------------------------------
// prep_k: 2048 blocks = 8 per batch (b = bid&255, i = bid>>8).
// Every block: load M (16x512) into registers (doubles as empty-flag scan),
//   recompute the gumbel ambiguity filter redundantly (no cross-block deps).
// i==0: metadata (cnt/list/emptyMask) + hm->out bulk copy (from registers).
// i==1: default one-hot(15) log rows.
// cnt>0 blocks: C0 rows [i*64,i*64+64) via register GEMM + butterfly reduce
//   (zero LDS in the inner loop), then one half of a q/cw GEMV per step
//   (step j, half h assigned to block i = (2j+h)&7).
// ---------------------------------------------------------------------------
__global__ __launch_bounds__(256) void prep_k(
    const float* __restrict__ his_mem, const float* __restrict__ states,
    const float* __restrict__ global_trace, const float* __restrict__ null_mem,
    const float* __restrict__ gumbel_u, const float* __restrict__ W,
    const float* __restrict__ attn_b, float* __restrict__ out,
    float* __restrict__ C0, float* __restrict__ qCache,
    float* __restrict__ cwCache, int* __restrict__ cnt_g,
    int* __restrict__ ambT_g, int* __restrict__ stepNz_g,
    int* __restrict__ emptyMask_g)
{
    const int bid = blockIdx.x;
    const int b = bid & 255;
    const int i = bid >> 8;
    const int tid = threadIdx.x;
    const int wave = tid >> 6, lane = tid & 63;

    __shared__ float empty_sh[kS];
    __shared__ unsigned char ambList[kN];
    __shared__ int wcnt[2];
    __shared__ int cnt_sh;
    __shared__ __align__(16) float Xs[1024];
    __shared__ int nz_sh;

    float* out_hm = out;
    float* out_log = out + (size_t)kB * kSlots * kM;

    // ---- load M into registers (lane l holds cols l*8..l*8+8 per slot) ----
    float4 m0[kS], m1[kS];
#pragma unroll
    for (int s = 0; s < kS; ++s) {
        const float* p = (s < kSlots) ? his_mem + ((size_t)b * kSlots + s) * kM
                                      : null_mem + (size_t)b * kM;
        m0[s] = *(const float4*)(p + lane * 8);
        m1[s] = *(const float4*)(p + lane * 8 + 4);
        int nz = (m0[s].x != 0.f) | (m0[s].y != 0.f) | (m0[s].z != 0.f) |
                 (m0[s].w != 0.f) | (m1[s].x != 0.f) | (m1[s].y != 0.f) |
                 (m1[s].z != 0.f) | (m1[s].w != 0.f);
        unsigned long long bal = __ballot(nz);   // wave-local, full 512 cols
        if (tid == 0) empty_sh[s] = (bal == 0ull) ? 1.f : 0.f;
    }
    __syncthreads();

    // ---- ambiguity filter (redundant per block; thread t = step t) ----
    bool amb = false;
    if (tid < kN) {
        const int idx = b * kN + tid;
        const float* up = gumbel_u + (size_t)idx * kS;
        float g[kS];
#pragma unroll
        for (int s = 0; s < kS; ++s) {
            float u = fminf(fmaxf(up[s], 1e-20f), 1.0f);
            g[s] = -logf(-logf(u) + 1e-20f);
        }
        float rhs = g[15] + 10.f * empty_sh[15] - 1.01f;
#pragma unroll
        for (int s = 0; s < kSlots; ++s)
            amb = amb || (g[s] + 10.f * empty_sh[s] >= rhs);
    }
    unsigned long long m = __ballot(amb);
    if (tid < kN && (tid & 63) == 0) wcnt[tid >> 6] = __popcll(m);
    __syncthreads();
    if (tid < kN && amb) {
        int base = (tid >= 64) ? wcnt[0] : 0;
        int pos = base + __popcll(m & ((1ull << (tid & 63)) - 1ull));
        ambList[pos] = (unsigned char)tid;       // ascending step order
    }
    if (tid == 0) cnt_sh = wcnt[0] + wcnt[1];
    __syncthreads();
    const int cnt = cnt_sh;

    // ---- chores ----
    if (i == 0) {
        if (tid == 0) {
            cnt_g[b] = cnt;
            int mk = 0;
#pragma unroll
            for (int s = 0; s < kS; ++s) mk |= (empty_sh[s] != 0.f) << s;
            emptyMask_g[b] = mk;
        }
        if (tid < kN && tid < cnt) ambT_g[b * kN + tid] = (int)ambList[tid];
        // hm bulk copy straight from registers
        for (int s = wave; s < kSlots; s += 4) {
            float* d = out_hm + ((size_t)b * kSlots + s) * kM + lane * 8;
            // s is runtime here: select via unrolled switch-free gather
            float4 a, c;
#pragma unroll
            for (int ss = 0; ss < kSlots; ++ss)
                if (ss == s) { a = m0[ss]; c = m1[ss]; }
            *(float4*)d = a;
            *(float4*)(d + 4) = c;
        }
    }
    if (i == 1 && tid < kN) {
        float* lp = out_log + ((size_t)b * kN + tid) * kS;
        float4 zz = make_float4(0.f, 0.f, 0.f, 0.f);
        *(float4*)(lp + 0) = zz;
        *(float4*)(lp + 4) = zz;
        *(float4*)(lp + 8) = zz;
        *(float4*)(lp + 12) = make_float4(0.f, 0.f, 0.f, 1.f);
    }
    if (cnt == 0) return;

    // ---- C0 register GEMM: rows [i*64 + wave*16, +16) ----
    {
        const int rbase = i * 64 + wave * 16;
        const float* wp = W + (size_t)rbase * kW + 1024 + lane * 8;
        float4 wa = *(const float4*)wp;
        float4 wb = *(const float4*)(wp + 4);
        const int b0 = lane & 1, b1 = (lane >> 1) & 1;
        const int b2 = (lane >> 2) & 1, b3 = (lane >> 3) & 1;
        for (int rl = 0; rl < 16; ++rl) {
            const int rn = (rl < 15) ? rl + 1 : rl;           // clamp prefetch
            const float* np = W + (size_t)(rbase + rn) * kW + 1024 + lane * 8;
            float4 na = *(const float4*)np;
            float4 nb = *(const float4*)(np + 4);
            float acc[kS];
#pragma unroll
            for (int s = 0; s < kS; ++s) {
                float a = m0[s].x * wa.x;
                a = fmaf(m0[s].y, wa.y, a);
                a = fmaf(m0[s].z, wa.z, a);
                a = fmaf(m0[s].w, wa.w, a);
                a = fmaf(m1[s].x, wb.x, a);
                a = fmaf(m1[s].y, wb.y, a);
                a = fmaf(m1[s].z, wb.z, a);
                a = fmaf(m1[s].w, wb.w, a);
                acc[s] = a;
            }
            // butterfly: 16 slot-sums over 64 lanes -> lane (l&15) = slot sum
            float v8[8];
#pragma unroll
            for (int j = 0; j < 8; ++j) {
                float keep = b0 ? acc[2 * j + 1] : acc[2 * j];
                float send = b0 ? acc[2 * j] : acc[2 * j + 1];
                v8[j] = keep + __shfl_xor(send, 1);
            }
            float v4[4];
#pragma unroll
            for (int j = 0; j < 4; ++j) {
                float keep = b1 ? v8[2 * j + 1] : v8[2 * j];
                float send = b1 ? v8[2 * j] : v8[2 * j + 1];
                v4[j] = keep + __shfl_xor(send, 2);
            }
            float v2[2];
#pragma unroll
            for (int j = 0; j < 2; ++j) {
                float keep = b2 ? v4[2 * j + 1] : v4[2 * j];
                float send = b2 ? v4[2 * j] : v4[2 * j + 1];
                v2[j] = keep + __shfl_xor(send, 4);
            }
            float keep = b3 ? v2[1] : v2[0];
            float send = b3 ? v2[0] : v2[1];
            float y = keep + __shfl_xor(send, 8);
            y += __shfl_xor(y, 16);
            y += __shfl_xor(y, 32);
            if (lane < kS)
                C0[((size_t)b * kS + lane) * kM + rbase + rl] = y;
            wa = na; wb = nb;
        }
    }

    // ---- q/cw GEMV halves: block i owns (j,h) with (2j+h)&7 == i ----
    const int h = i & 1;
    for (int j = (i >> 1); j < cnt && j < kQC; j += 4) {
        const int t = ambList[j];
        const int idx = b * kN + t;
        __syncthreads();
        if (tid == 0) nz_sh = 0;
        __syncthreads();
        float s0 = states[(size_t)idx * kM + tid];
        float s1 = states[(size_t)idx * kM + 256 + tid];
        Xs[tid] = s0; Xs[256 + tid] = s1;
        Xs[512 + tid] = global_trace[(size_t)b * kM + tid];
        Xs[768 + tid] = global_trace[(size_t)b * kM + 256 + tid];
        if (s0 != 0.f || s1 != 0.f) nz_sh = 1;
        __syncthreads();

        const int g = tid >> 4, l = tid & 15;
        const int koff = l * 4;
        for (int rr = 0; rr < 16; ++rr) {
            const int r = h * 256 + rr * 16 + g;
            const float* wr = W + (size_t)r * kW;
            float accq = 0.f, accc = 0.f;
#pragma unroll
            for (int q = 0; q < 16; ++q) {
                float4 wv = *(const float4*)(wr + koff + q * 64);
                float4 xv = *(const float4*)&Xs[koff + q * 64];
                accq = fmaf(wv.x, xv.x, accq); accq = fmaf(wv.y, xv.y, accq);
                accq = fmaf(wv.z, xv.z, accq); accq = fmaf(wv.w, xv.w, accq);
            }
#pragma unroll
            for (int q = 0; q < 8; ++q) {
                float4 wv = *(const float4*)(wr + 1024 + koff + q * 64);
                float4 xv = *(const float4*)&Xs[koff + q * 64];
                accc = fmaf(wv.x, xv.x, accc); accc = fmaf(wv.y, xv.y, accc);
                accc = fmaf(wv.z, xv.z, accc); accc = fmaf(wv.w, xv.w, accc);
            }
            accq += __shfl_xor(accq, 1); accq += __shfl_xor(accq, 2);
            accq += __shfl_xor(accq, 4); accq += __shfl_xor(accq, 8);
            accc += __shfl_xor(accc, 1); accc += __shfl_xor(accc, 2);
            accc += __shfl_xor(accc, 4); accc += __shfl_xor(accc, 8);
            if (l == 0) {
                qCache[((size_t)b * kQC + j) * kM + r] = accq + attn_b[r];
                cwCache[((size_t)b * kQC + j) * kM + r] = accc;
            }
        }
        if (tid == 0 && h == 0) stepNz_g[b * kQC + j] = nz_sh;
    }
}

// ---------------------------------------------------------------------------
// walk_k: 256 blocks, one per batch; exits immediately when cnt==0.
// Serial walk over flagged steps with everything pre-cached; inline q/cw
// recompute fallback only for j >= kQC (never for the real input).
// ---------------------------------------------------------------------------
__global__ __launch_bounds__(256) void walk_k(
    const float* __restrict__ states, const float* __restrict__ states_mask,
    const float* __restrict__ global_trace, const float* __restrict__ gumbel_u,
    const float* __restrict__ W, const float* __restrict__ attn_b,
    const float* __restrict__ v, const float* __restrict__ C0,
    const float* __restrict__ qCache, const float* __restrict__ cwCache,
    const int* __restrict__ cnt_g, const int* __restrict__ ambT_g,
    const int* __restrict__ stepNz_g, const int* __restrict__ emptyMask_g,
    float* __restrict__ out)
{
    const int b = blockIdx.x;
    const int cnt = cnt_g[b];
    if (cnt == 0) return;
    const int tid = threadIdx.x;

    float* out_hm = out;
    float* out_log = out + (size_t)kB * kSlots * kM;

    __shared__ __align__(16) float Cs[kS * kCsStride];
    __shared__ __align__(16) float Xq[1024];
    __shared__ __align__(16) float Qs[kM];
    __shared__ __align__(16) float vs[kM];
    __shared__ float empty_p[kS];
    __shared__ float e_sh[kS];
    __shared__ unsigned char listS[kN];
    __shared__ int slot_src[kSlots];
    __shared__ int k_sh, wk_sh, nz_sh;

    for (int idx = tid; idx < kS * kM; idx += 256) {
        int s = idx >> 9, r = idx & 511;
        Cs[s * kCsStride + r] = C0[((size_t)b * kS + s) * kM + r];
    }
    for (int idx = tid; idx < kM; idx += 256) {
        vs[idx] = v[idx];
        Xq[512 + idx] = global_trace[(size_t)b * kM + idx];
    }
    if (tid < kS) {
        int mk = emptyMask_g[b];
        empty_p[tid] = (mk >> tid) & 1 ? 1.f : 0.f;
    }
    if (tid < kSlots) slot_src[tid] = -1;
    if (tid < kN && tid < cnt) listS[tid] = (unsigned char)ambT_g[b * kN + tid];
    __syncthreads();

    const int sidx = tid >> 4;
    const int ml = tid & 15;
    const int g = tid >> 4, l = tid & 15;
    const int koff = l * 4;

    for (int jj = 0; jj < cnt; ++jj) {
        const int t = listS[jj];
        const int idx = b * kN + t;
        const float* qp;
        if (jj < kQC) {
            qp = qCache + ((size_t)b * kQC + jj) * kM;
        } else {
            // fallback: inline q GEMV (dead for real inputs)
            if (tid == 0) nz_sh = 0;
            __syncthreads();
            float s0 = states[(size_t)idx * kM + tid];
            float s1 = states[(size_t)idx * kM + 256 + tid];
            Xq[tid] = s0; Xq[256 + tid] = s1;
            if (s0 != 0.f || s1 != 0.f) nz_sh = 1;
            __syncthreads();
            for (int r0 = 0; r0 < kM; r0 += 16) {
                int r = r0 + g;
                const float* wr = W + (size_t)r * kW;
                float a = 0.f;
#pragma unroll
                for (int q = 0; q < 16; ++q) {
                    float4 wv = *(const float4*)(wr + koff + q * 64);
                    float4 xv = *(const float4*)&Xq[koff + q * 64];
                    a = fmaf(wv.x, xv.x, a); a = fmaf(wv.y, xv.y, a);
                    a = fmaf(wv.z, xv.z, a); a = fmaf(wv.w, xv.w, a);
                }
                a += __shfl_xor(a, 1); a += __shfl_xor(a, 2);
                a += __shfl_xor(a, 4); a += __shfl_xor(a, 8);
                if (l == 0) Qs[r] = a + attn_b[r];
            }
            __syncthreads();
            qp = Qs;
        }

        // e[s] = sum_m v[m] * tanh(q[m] + Cs[s][m])
        {
            const float* crow = &Cs[sidx * kCsStride];
            float acc = 0.f;
#pragma unroll
            for (int j = 0; j < 8; ++j) {
                int mcol = ml * 4 + j * 64;
                float4 q4 = *(const float4*)(qp + mcol);
                float4 c4 = *(const float4*)&crow[mcol];
                float4 v4 = *(const float4*)&vs[mcol];
                acc = fmaf(v4.x, tanh_fast(q4.x + c4.x), acc);
                acc = fmaf(v4.y, tanh_fast(q4.y + c4.y), acc);
                acc = fmaf(v4.z, tanh_fast(q4.z + c4.z), acc);
                acc = fmaf(v4.w, tanh_fast(q4.w + c4.w), acc);
            }
            acc += __shfl_xor(acc, 1); acc += __shfl_xor(acc, 2);
            acc += __shfl_xor(acc, 4); acc += __shfl_xor(acc, 8);
            if (ml == 0) e_sh[sidx] = acc;
        }
        __syncthreads();

        // wave 0: softmax + empty mask + gumbel + first-max argmax
        if (tid < 64) {
            int s = tid;
            float ev = (s < kS) ? e_sh[s] : -3.0e38f;
            float mx = ev;
            mx = fmaxf(mx, __shfl_xor(mx, 1));
            mx = fmaxf(mx, __shfl_xor(mx, 2));
            mx = fmaxf(mx, __shfl_xor(mx, 4));
            mx = fmaxf(mx, __shfl_xor(mx, 8));
            float w = (s < kS) ? __expf(ev - mx) : 0.f;
            float sm = w;
            sm += __shfl_xor(sm, 1); sm += __shfl_xor(sm, 2);
            sm += __shfl_xor(sm, 4); sm += __shfl_xor(sm, 8);
            w = w / sm;
            w += 10.0f * ((s < kS) ? empty_p[s] : 0.f);
            float z;
            if (s < kS) {
                float u = gumbel_u[(size_t)idx * kS + s];
                u = fminf(fmaxf(u, 1e-20f), 1.0f);
                float gn = -logf(-logf(u) + 1e-20f);
                z = w + gn;           // tau = 1.0
            } else z = -3.0e38f;
            float zm = z;
            zm = fmaxf(zm, __shfl_xor(zm, 1));
            zm = fmaxf(zm, __shfl_xor(zm, 2));
            zm = fmaxf(zm, __shfl_xor(zm, 4));
            zm = fmaxf(zm, __shfl_xor(zm, 8));
            unsigned long long bal = __ballot(z == zm) & 0xFFFFull;
            if (s == 0) k_sh = __ffsll(bal) - 1;   // first-max (jnp.argmax)
        }
        __syncthreads();

        const int k = k_sh;
        if (tid < kS)
            out_log[(size_t)idx * kS + tid] = (tid == k) ? 1.f : 0.f;
        if (tid == 0) {
            float mv = states_mask[idx];
            wk_sh = (k < kSlots && mv != 0.0f) ? k : -1;
        }
        __syncthreads();

        const int wk = wk_sh;
        if (wk >= 0) {
            if (jj < kQC) {
                Cs[wk * kCsStride + tid] =
                    cwCache[((size_t)b * kQC + jj) * kM + tid];
                Cs[wk * kCsStride + 256 + tid] =
                    cwCache[((size_t)b * kQC + jj) * kM + 256 + tid];
                if (tid == 0) {
                    slot_src[wk] = t;
                    empty_p[wk] = stepNz_g[b * kQC + jj] ? 0.f : 1.f;
                }
            } else {
                // fallback: inline cw GEMV from staged Xq (dead normally)
                for (int r0 = 0; r0 < kM; r0 += 16) {
                    int r = r0 + g;
                    const float* wr = W + (size_t)r * kW + 1024;
                    float ca = 0.f;
#pragma unroll
                    for (int q = 0; q < 8; ++q) {
                        float4 wv = *(const float4*)(wr + koff + q * 64);
                        float4 xv = *(const float4*)&Xq[koff + q * 64];
                        ca = fmaf(wv.x, xv.x, ca); ca = fmaf(wv.y, xv.y, ca);
                        ca = fmaf(wv.z, xv.z, ca); ca = fmaf(wv.w, xv.w, ca);
                    }
                    ca += __shfl_xor(ca, 1); ca += __shfl_xor(ca, 2);
                    ca += __shfl_xor(ca, 4); ca += __shfl_xor(ca, 8);
                    if (l == 0) Cs[wk * kCsStride + r] = ca;
                }
                __syncthreads();
                if (tid == 0) {
                    slot_src[wk] = t;
                    empty_p[wk] = nz_sh ? 0.f : 1.f;
                }
            }
        }
        __syncthreads();
    }

    // epilogue: overwrite written slots only (bulk copy done in prep_k)
    for (int s = 0; s < kSlots; ++s) {
        int ts = slot_src[s];
        if (ts >= 0) {
            float* dst = out_hm + ((size_t)b * kSlots + s) * kM;
            dst[tid] = states[((size_t)b * kN + ts) * kM + tid];
            dst[tid + 256] = states[((size_t)b * kN + ts) * kM + tid + 256];
        }
    }
}

// ---------------------------------------------------------------------------
extern "C" void kernel_launch(void* const* d_in, const int* in_sizes, int n_in,
                              void* d_out, int out_size, void* d_ws, size_t ws_size,
                              hipStream_t stream)
{
    const float* his_mem      = (const float*)d_in[0];
    const float* states       = (const float*)d_in[1];
    const float* states_mask  = (const float*)d_in[2];
    const float* global_trace = (const float*)d_in[3];
    const float* null_mem     = (const float*)d_in[4];
    const float* gumbel_u     = (const float*)d_in[5];
    const float* attn_W       = (const float*)d_in[6];
    const float* attn_b       = (const float*)d_in[7];
    const float* v            = (const float*)d_in[8];

    // ws (~24.2 MB), no memset needed (walk reads only cnt>0-guarded data):
    //   C0      [256*16*512] f32  (8 MB)
    //   qCache  [256*16*512] f32  (8 MB)
    //   cwCache [256*16*512] f32  (8 MB)
    //   cnt_g[256] | ambT_g[256*128] | stepNz_g[256*16] | emptyMask_g[256]
    float* C0 = (float*)d_ws;
    float* qCache = C0 + (size_t)kB * kS * kM;
    float* cwCache = qCache + (size_t)kB * kQC * kM;
    int* cnt_g = (int*)(cwCache + (size_t)kB * kQC * kM);
    int* ambT_g = cnt_g + kB;
    int* stepNz_g = ambT_g + kB * kN;
    int* emptyMask_g = stepNz_g + kB * kQC;

    prep_k<<<2048, 256, 0, stream>>>(his_mem, states, global_trace, null_mem,
                                     gumbel_u, attn_W, attn_b, (float*)d_out,
                                     C0, qCache, cwCache, cnt_g, ambT_g,
                                     stepNz_g, emptyMask_g);
    walk_k<<<kB, 256, 0, stream>>>(states, states_mask, global_trace, gumbel_u,
                                   attn_W, attn_b, v, C0, qCache, cwCache,
                                   cnt_g, ambT_g, stepNz_g, emptyMask_g,
                                   (float*)d_out);
}

// Round 4
// 173.637 us; speedup vs baseline: 1.9910x; 1.4754x over previous
//
#include <hip/hip_runtime.h>

// Problem constants (fixed by setup_inputs)
constexpr int kB = 256;      // batch
constexpr int kN = 128;      // seq len
constexpr int kM = 512;      // mem width
constexpr int kSlots = 15;   // his_mem slots
constexpr int kS = 16;       // slots incl. null
constexpr int kW = 1536;     // attn_W row length (d_q + M)
constexpr int kCap = 4096;   // cached ambiguous-step capacity (n~66 measured)
constexpr size_t kC0Half = (size_t)kB * kS * kM;  // elems per split-K partial

__device__ __forceinline__ float tanh_fast(float x)
{
    float xc = fminf(15.f, fmaxf(-15.f, x));
    float ex = __expf(2.f * xc);
    return 1.f - 2.f * __builtin_amdgcn_rcpf(ex + 1.f);
}

// ---------------------------------------------------------------------------
// prep1: one block per batch. Fuses: empty-slot flags, bulk hm copy
// (out_hm = his_mem), gumbel ambiguity filter (fast-log: the -1.01 margin
// absorbs ~1e-5 approx error; the EXACT gumbel is recomputed in phaseB),
// default one-hot(15) log rows, and compact list building.
// cnt/total zeroed by a preceding hipMemsetAsync.
// ---------------------------------------------------------------------------
__global__ __launch_bounds__(256) void prep1_k(
    const float* __restrict__ his_mem, const float* __restrict__ null_mem,
    const float* __restrict__ gumbel_u, float* __restrict__ out,
    int* __restrict__ empty0, int* __restrict__ cnt, int* __restrict__ total,
    unsigned* __restrict__ list, int* __restrict__ listPos,
    int* __restrict__ ambBatch, unsigned char* __restrict__ amb_flags)
{
    const int b = blockIdx.x;
    const int tid = threadIdx.x;
    const int wave = tid >> 6, lane = tid & 63;
    __shared__ int eflag[kS];
    float* out_hm = out;
    float* out_log = out + (size_t)kB * kSlots * kM;

    // empty flags + hm copy: each of 4 waves handles 4 slot-rows
    for (int s = wave; s < kS; s += 4) {
        const float* p = (s < kSlots) ? his_mem + (size_t)(b * kSlots + s) * kM
                                      : null_mem + (size_t)b * kM;
        float4 v0 = *(const float4*)(p + lane * 4);
        float4 v1 = *(const float4*)(p + 256 + lane * 4);
        int nz = (v0.x != 0.f) | (v0.y != 0.f) | (v0.z != 0.f) | (v0.w != 0.f) |
                 (v1.x != 0.f) | (v1.y != 0.f) | (v1.z != 0.f) | (v1.w != 0.f);
        unsigned long long bal = __ballot(nz);
        if (lane == 0) eflag[s] = (bal == 0ull) ? 1 : 0;
        if (s < kSlots) {
            float* dst = out_hm + (size_t)(b * kSlots + s) * kM;
            *(float4*)(dst + lane * 4) = v0;
            *(float4*)(dst + 256 + lane * 4) = v1;
        }
    }
    __syncthreads();
    if (tid < kS) empty0[b * kS + tid] = eflag[tid];

    // filter: threads 0..127 each own step t = tid
    if (tid < kN) {
        const int idx = b * kN + tid;
        const float* up = gumbel_u + (size_t)idx * kS;
        float g[kS];
#pragma unroll
        for (int s = 0; s < kS; ++s) {
            float u = fminf(fmaxf(up[s], 1e-20f), 1.0f);
            g[s] = -__logf(-__logf(u) + 1e-20f);
        }
        float rhs = g[15] + 10.f * (eflag[15] ? 1.f : 0.f) - 1.01f;
        bool amb = false;
#pragma unroll
        for (int s = 0; s < kSlots; ++s)
            amb = amb || (g[s] + 10.f * (eflag[s] ? 1.f : 0.f) >= rhs);
        amb_flags[idx] = amb ? 1 : 0;
        if (amb) {
            int pos = atomicAdd(&total[0], 1);
            if (pos < kCap) list[pos] = (unsigned)idx;
            listPos[idx] = pos;
            int prev = atomicAdd(&cnt[b], 1);
            if (prev == 0) {
                int bp = atomicAdd(&total[1], 1);
                ambBatch[bp] = b;
            }
        }
        float* lp = out_log + (size_t)idx * kS;
        float4 zz = make_float4(0.f, 0.f, 0.f, 0.f);
        *(float4*)(lp + 0) = zz;
        *(float4*)(lp + 4) = zz;
        *(float4*)(lp + 8) = zz;
        *(float4*)(lp + 12) = make_float4(0.f, 0.f, 0.f, 1.f);
    }
}

// ---------------------------------------------------------------------------
// prep2: fused split-K c0-GEMM (blocks 0..1023) + qcw GEMV chunks (blocks
// 1024..2559). Split-K=2 doubles GEMM concurrency and halves per-block LDS
// traffic (the GEMM is LDS-pipe-bound at 2 ds_read_b128 / 16 MACs); phaseB
// sums the two C0 partials during its Cs load.
//
// c0 path: C0[kh][b*16+s][m] = W[m][1024+kh*256 : +256] . mem[b,s][kh*256:+256]
//   gathered over the compacted ambiguous-batch list (4 batches = 64 rows/tile).
// qcw path: per cached ambiguous step i and 32-row chunk j:
//   q[r]  = bias[r] + W[r][0:1024] . [state|gt]
//   cw[r] = W[r][1024:1536] . state      (C-row if this step writes)
//   stepNz[i] = any(state != 0)
// ---------------------------------------------------------------------------
__global__ __launch_bounds__(256) void prep2_k(
    const float* __restrict__ W, const float* __restrict__ his_mem,
    const float* __restrict__ null_mem, const float* __restrict__ states,
    const float* __restrict__ global_trace, const float* __restrict__ attn_b,
    const int* __restrict__ total, const int* __restrict__ ambBatch,
    const unsigned* __restrict__ list, float* __restrict__ C0,
    float* __restrict__ qCache, float* __restrict__ cwCache,
    int* __restrict__ stepNz)
{
    const int tid = threadIdx.x;

    if (blockIdx.x < 1024) {
        // ------------------------- c0 GEMM path (split-K=2) ----------------
        const int nab = total[1];
        const int kh = blockIdx.x & 1;           // K-half
        const int cxy = (int)blockIdx.x >> 1;    // 0..511
        const int cx = cxy >> 3;                 // 0..63  (row tiles)
        const int cy = cxy & 7;                  // 0..7   (col tiles)
        if (cx * 4 >= nab) return;
        __shared__ float As[16 * 68];
        __shared__ float Bs[16 * 68];
        const int n0 = cy * 64;
        const int row_l = tid >> 2;
        const int k4 = (tid & 3) * 4;
        const int ty = tid >> 4, tx = tid & 15;

        int bi = cx * 4 + (row_l >> 4);
        if (bi >= nab) bi = nab - 1;             // clamp: redundant work only
        const int b = ambBatch[bi];
        const int s = row_l & 15;
        const float* ap = ((s < kSlots) ? (his_mem + (size_t)(b * kSlots + s) * kM)
                                        : (null_mem + (size_t)b * kM)) + kh * 256;
        const float* wp = W + (size_t)(n0 + row_l) * kW + 1024 + kh * 256;

        float acc[4][4];
#pragma unroll
        for (int i = 0; i < 4; ++i)
#pragma unroll
            for (int j = 0; j < 4; ++j) acc[i][j] = 0.f;

        for (int kt = 0; kt < 256; kt += 16) {
            float4 a4 = *(const float4*)(ap + kt + k4);
            float4 b4 = *(const float4*)(wp + kt + k4);
            __syncthreads();
            As[(k4 + 0) * 68 + row_l] = a4.x; As[(k4 + 1) * 68 + row_l] = a4.y;
            As[(k4 + 2) * 68 + row_l] = a4.z; As[(k4 + 3) * 68 + row_l] = a4.w;
            Bs[(k4 + 0) * 68 + row_l] = b4.x; Bs[(k4 + 1) * 68 + row_l] = b4.y;
            Bs[(k4 + 2) * 68 + row_l] = b4.z; Bs[(k4 + 3) * 68 + row_l] = b4.w;
            __syncthreads();
#pragma unroll
            for (int k = 0; k < 16; ++k) {
                const float4 av = *(const float4*)&As[k * 68 + ty * 4];
                const float4 bv = *(const float4*)&Bs[k * 68 + tx * 4];
                acc[0][0] = fmaf(av.x, bv.x, acc[0][0]);
                acc[0][1] = fmaf(av.x, bv.y, acc[0][1]);
                acc[0][2] = fmaf(av.x, bv.z, acc[0][2]);
                acc[0][3] = fmaf(av.x, bv.w, acc[0][3]);
                acc[1][0] = fmaf(av.y, bv.x, acc[1][0]);
                acc[1][1] = fmaf(av.y, bv.y, acc[1][1]);
                acc[1][2] = fmaf(av.y, bv.z, acc[1][2]);
                acc[1][3] = fmaf(av.y, bv.w, acc[1][3]);
                acc[2][0] = fmaf(av.z, bv.x, acc[2][0]);
                acc[2][1] = fmaf(av.z, bv.y, acc[2][1]);
                acc[2][2] = fmaf(av.z, bv.z, acc[2][2]);
                acc[2][3] = fmaf(av.z, bv.w, acc[2][3]);
                acc[3][0] = fmaf(av.w, bv.x, acc[3][0]);
                acc[3][1] = fmaf(av.w, bv.y, acc[3][1]);
                acc[3][2] = fmaf(av.w, bv.z, acc[3][2]);
                acc[3][3] = fmaf(av.w, bv.w, acc[3][3]);
            }
        }
#pragma unroll
        for (int i = 0; i < 4; ++i) {
            int rl = ty * 4 + i;
            int bij = cx * 4 + (rl >> 4);
            if (bij >= nab) bij = nab - 1;
            int ro = ambBatch[bij] * kS + (rl & 15);
            float4 o = make_float4(acc[i][0], acc[i][1], acc[i][2], acc[i][3]);
            *(float4*)(C0 + kh * kC0Half + (size_t)ro * kM + n0 + tx * 4) = o;
        }
    } else {
        // ------------------------- qcw GEMV path --------------------------
        int n = total[0];
        if (n > kCap) n = kCap;
        __shared__ float Xs[1024];
        __shared__ int nzs;

        for (int c = (int)blockIdx.x - 1024; c < n * 16; c += 1536) {
            const int i = c >> 4;        // step index in list
            const int j = c & 15;        // 32-row chunk
            const int idx = (int)list[i];
            const int b = idx >> 7;
            __syncthreads();             // protect Xs reuse across iterations
            if (tid == 0) nzs = 0;
            __syncthreads();
            float s0 = states[(size_t)idx * kM + tid];
            float s1 = states[(size_t)idx * kM + 256 + tid];
            Xs[tid] = s0; Xs[256 + tid] = s1;
            Xs[512 + tid] = global_trace[(size_t)b * kM + tid];
            Xs[768 + tid] = global_trace[(size_t)b * kM + 256 + tid];
            if (s0 != 0.f || s1 != 0.f) nzs = 1;
            __syncthreads();

            const int g = tid >> 4;      // 0..15 row group
            const int l = tid & 15;      // lane in group
#pragma unroll
            for (int p = 0; p < 2; ++p) {
                const int r = j * 32 + p * 16 + g;
                const float* wr = W + (size_t)r * kW;
                float accq = 0.f, accc = 0.f;
#pragma unroll
                for (int jj = 0; jj < 16; ++jj) {
                    int k = l * 4 + jj * 64;
                    float4 w4 = *(const float4*)(wr + k);
                    float4 x4 = *(const float4*)&Xs[k];
                    accq = fmaf(w4.x, x4.x, accq); accq = fmaf(w4.y, x4.y, accq);
                    accq = fmaf(w4.z, x4.z, accq); accq = fmaf(w4.w, x4.w, accq);
                }
#pragma unroll
                for (int jj = 0; jj < 8; ++jj) {
                    int k = l * 4 + jj * 64;
                    float4 w4 = *(const float4*)(wr + 1024 + k);
                    float4 x4 = *(const float4*)&Xs[k];
                    accc = fmaf(w4.x, x4.x, accc); accc = fmaf(w4.y, x4.y, accc);
                    accc = fmaf(w4.z, x4.z, accc); accc = fmaf(w4.w, x4.w, accc);
                }
                accq += __shfl_xor(accq, 1); accq += __shfl_xor(accq, 2);
                accq += __shfl_xor(accq, 4); accq += __shfl_xor(accq, 8);
                accc += __shfl_xor(accc, 1); accc += __shfl_xor(accc, 2);
                accc += __shfl_xor(accc, 4); accc += __shfl_xor(accc, 8);
                if (l == 0) {
                    qCache[(size_t)i * kM + r] = accq + attn_b[r];
                    cwCache[(size_t)i * kM + r] = accc;
                }
            }
            if (tid == 0 && j == 0) stepNz[i] = nzs;
        }
    }
}

// ---------------------------------------------------------------------------
// Phase B: per ambiguous batch, walk flagged steps in order. Serial chain is
// W-free: e-eval from qCache + LDS C; writes copy cwCache into LDS.
// Cs load sums the two split-K C0 partials.
// (Inline recompute fallback only if listPos >= kCap — never with real input.)
// ---------------------------------------------------------------------------
constexpr int kCsStride = 528;   // 512+16 -> at most 2-way bank aliasing (free)

__global__ __launch_bounds__(256) void phaseB_k(
    const float* __restrict__ C0, const int* __restrict__ empty0,
    const unsigned char* __restrict__ amb_flags, const int* __restrict__ cnt,
    const int* __restrict__ listPos, const float* __restrict__ qCache,
    const float* __restrict__ cwCache, const int* __restrict__ stepNz,
    const float* __restrict__ states, const float* __restrict__ states_mask,
    const float* __restrict__ gumbel_u, const float* __restrict__ global_trace,
    const float* __restrict__ W, const float* __restrict__ attn_b,
    const float* __restrict__ v, float* __restrict__ out)
{
    const int b = blockIdx.x;
    if (cnt[b] == 0) return;     // defaults already correct
    const int tid = threadIdx.x;
    float* out_hm = out;
    float* out_log = out + (size_t)kB * kSlots * kM;

    __shared__ float Cs[kS * kCsStride];
    __shared__ float Xb[1024];          // [state | gt] — fallback path only
    __shared__ float Qb[kM];            // fallback q
    __shared__ float vs[kM];
    __shared__ float e_sh[kS];
    __shared__ float empty_sh[kS];
    __shared__ unsigned char flS[kN];
    __shared__ int slot_src[kSlots];
    __shared__ int k_sh, wk_sh, nz_sh;

    for (int i = tid; i < kS * kM; i += 256) {
        int s = i >> 9, m = i & 511;
        Cs[s * kCsStride + m] = C0[(size_t)(b * kS + s) * kM + m] +
                                C0[kC0Half + (size_t)(b * kS + s) * kM + m];
    }
    for (int i = tid; i < kM; i += 256) {
        vs[i] = v[i];
        Xb[512 + i] = global_trace[(size_t)b * kM + i];
    }
    if (tid < kS) empty_sh[tid] = empty0[b * kS + tid] ? 1.0f : 0.0f;
    if (tid < kSlots) slot_src[tid] = -1;
    if (tid < kN) flS[tid] = amb_flags[b * kN + tid];
    __syncthreads();

    const int sidx = tid >> 4;   // slot handled by this thread
    const int ml = tid & 15;     // lane within slot group

    for (int t = 0; t < kN; ++t) {
        if (!flS[t]) continue;

        const int pos = listPos[b * kN + t];
        const float* qp;
        if (pos < kCap) {
            qp = qCache + (size_t)pos * kM;
        } else {
            // fallback: recompute q inline (dead code for real inputs)
            Xb[tid] = states[(size_t)(b * kN + t) * kM + tid];
            Xb[256 + tid] = states[(size_t)(b * kN + t) * kM + 256 + tid];
            __syncthreads();
            const int g2 = tid >> 4, l2 = tid & 15;
            for (int r0 = 0; r0 < kM; r0 += 16) {
                int r = r0 + g2;
                const float* wr = W + (size_t)r * kW;
                float a = 0.f;
                for (int k = l2 * 4; k < 1024; k += 64) {
                    float4 w4 = *(const float4*)(wr + k);
                    float4 x4 = *(const float4*)&Xb[k];
                    a = fmaf(w4.x, x4.x, a); a = fmaf(w4.y, x4.y, a);
                    a = fmaf(w4.z, x4.z, a); a = fmaf(w4.w, x4.w, a);
                }
                a += __shfl_xor(a, 1); a += __shfl_xor(a, 2);
                a += __shfl_xor(a, 4); a += __shfl_xor(a, 8);
                if (l2 == 0) Qb[r] = a + attn_b[r];
            }
            __syncthreads();
            qp = Qb;
        }

        // e[s] = sum_m v[m] * tanh(q[m] + C[s][m]); float4, 16 lanes/slot
        const float* crow = &Cs[sidx * kCsStride];
        float acc = 0.f;
#pragma unroll
        for (int j = 0; j < 8; ++j) {
            int m = ml * 4 + j * 64;
            float4 q4 = *(const float4*)(qp + m);
            float4 c4 = *(const float4*)&crow[m];
            float4 v4 = *(const float4*)&vs[m];
            acc = fmaf(v4.x, tanh_fast(q4.x + c4.x), acc);
            acc = fmaf(v4.y, tanh_fast(q4.y + c4.y), acc);
            acc = fmaf(v4.z, tanh_fast(q4.z + c4.z), acc);
            acc = fmaf(v4.w, tanh_fast(q4.w + c4.w), acc);
        }
        acc += __shfl_xor(acc, 1); acc += __shfl_xor(acc, 2);
        acc += __shfl_xor(acc, 4); acc += __shfl_xor(acc, 8);
        if (ml == 0) e_sh[sidx] = acc;
        __syncthreads();

        // wave 0: softmax + empty mask + gumbel + argmax
        if (tid < 64) {
            int s = tid;
            float ev = (s < kS) ? e_sh[s] : -3.0e38f;
            float mx = ev;
            mx = fmaxf(mx, __shfl_xor(mx, 1));
            mx = fmaxf(mx, __shfl_xor(mx, 2));
            mx = fmaxf(mx, __shfl_xor(mx, 4));
            mx = fmaxf(mx, __shfl_xor(mx, 8));
            float w = (s < kS) ? __expf(ev - mx) : 0.f;
            float sm = w;
            sm += __shfl_xor(sm, 1); sm += __shfl_xor(sm, 2);
            sm += __shfl_xor(sm, 4); sm += __shfl_xor(sm, 8);
            w = w / sm;
            w += 10.0f * ((s < kS) ? empty_sh[s] : 0.f);
            float z;
            if (s < kS) {
                float u = gumbel_u[(size_t)(b * kN + t) * kS + s];
                u = fminf(fmaxf(u, 1e-20f), 1.0f);
                float g = -logf(-logf(u) + 1e-20f);
                z = w + g;            // tau = 1.0
            } else z = -3.0e38f;
            float zm = z;
            zm = fmaxf(zm, __shfl_xor(zm, 1));
            zm = fmaxf(zm, __shfl_xor(zm, 2));
            zm = fmaxf(zm, __shfl_xor(zm, 4));
            zm = fmaxf(zm, __shfl_xor(zm, 8));
            unsigned long long bal = __ballot(z == zm) & 0xFFFFull;
            if (s == 0) k_sh = __ffsll(bal) - 1;   // first-max (jnp.argmax)
        }
        __syncthreads();

        const int k = k_sh;
        if (tid < kS) out_log[(size_t)(b * kN + t) * kS + tid] = (tid == k) ? 1.f : 0.f;
        if (tid == 0) {
            float mv = states_mask[b * kN + t];
            wk_sh = (k < kSlots && mv != 0.0f) ? k : -1;
            nz_sh = 0;
        }
        __syncthreads();

        const int wk = wk_sh;
        if (wk >= 0) {
            if (pos < kCap) {
                // cached: C-row copy + precomputed nz flag
                Cs[wk * kCsStride + tid] = cwCache[(size_t)pos * kM + tid];
                Cs[wk * kCsStride + 256 + tid] = cwCache[(size_t)pos * kM + 256 + tid];
                if (tid == 0) {
                    slot_src[wk] = t;
                    empty_sh[wk] = stepNz[pos] ? 0.f : 1.f;
                }
            } else {
                // fallback: inline cw GEMV from staged Xb (dead code normally)
                if (Xb[tid] != 0.f || Xb[256 + tid] != 0.f) nz_sh = 1;
                __syncthreads();
                const int g2 = tid >> 4, l2 = tid & 15;
                for (int r0 = 0; r0 < kM; r0 += 16) {
                    int r = r0 + g2;
                    const float* wr = W + (size_t)r * kW + 1024;
                    float ca = 0.f;
                    for (int k2 = l2 * 4; k2 < kM; k2 += 64) {
                        float4 w4 = *(const float4*)(wr + k2);
                        float4 x4 = *(const float4*)&Xb[k2];
                        ca = fmaf(w4.x, x4.x, ca); ca = fmaf(w4.y, x4.y, ca);
                        ca = fmaf(w4.z, x4.z, ca); ca = fmaf(w4.w, x4.w, ca);
                    }
                    ca += __shfl_xor(ca, 1); ca += __shfl_xor(ca, 2);
                    ca += __shfl_xor(ca, 4); ca += __shfl_xor(ca, 8);
                    if (l2 == 0) Cs[wk * kCsStride + r] = ca;
                }
                __syncthreads();
                if (tid == 0) {
                    slot_src[wk] = t;
                    empty_sh[wk] = nz_sh ? 0.f : 1.f;
                }
            }
        }
        __syncthreads();
    }

    // epilogue: overwrite written slots only (bulk copy already done)
    for (int s = 0; s < kSlots; ++s) {
        int ts = slot_src[s];
        if (ts >= 0) {
            float* dst = out_hm + (size_t)(b * kSlots + s) * kM;
            dst[tid] = states[(size_t)(b * kN + ts) * kM + tid];
            dst[tid + 256] = states[(size_t)(b * kN + ts) * kM + tid + 256];
        }
    }
}

// ---------------------------------------------------------------------------
extern "C" void kernel_launch(void* const* d_in, const int* in_sizes, int n_in,
                              void* d_out, int out_size, void* d_ws, size_t ws_size,
                              hipStream_t stream)
{
    const float* his_mem      = (const float*)d_in[0];
    const float* states       = (const float*)d_in[1];
    const float* states_mask  = (const float*)d_in[2];
    const float* global_trace = (const float*)d_in[3];
    const float* null_mem     = (const float*)d_in[4];
    const float* gumbel_u     = (const float*)d_in[5];
    const float* attn_W       = (const float*)d_in[6];
    const float* attn_b       = (const float*)d_in[7];
    const float* v            = (const float*)d_in[8];

    // ws layout (~32.5 MB):
    //   C0      [2][4096*512] f32  (16 MB, split-K partials)
    //   qCache  [4096*512] f32     ( 8 MB)
    //   cwCache [4096*512] f32     ( 8 MB)
    //   cnt[256] i32 | total[16] i32            <- zeroed by one memset
    //   empty0[4096] i32 | ambBatch[256] i32 | stepNz[4096] i32
    //   listPos[32768] i32 | list[32768] u32 | amb[32768] u8
    float* C0 = (float*)d_ws;
    float* qCache = C0 + 2 * kC0Half;
    float* cwCache = qCache + (size_t)kCap * kM;
    int* cnt = (int*)(cwCache + (size_t)kCap * kM);
    int* total = cnt + kB;
    int* empty0 = total + 16;
    int* ambBatch = empty0 + kB * kS;
    int* stepNz = ambBatch + kB;
    int* listPos = stepNz + kCap;
    unsigned* list = (unsigned*)(listPos + kB * kN);
    unsigned char* amb = (unsigned char*)(list + kB * kN);

    hipMemsetAsync(cnt, 0, (kB + 16) * sizeof(int), stream);
    prep1_k<<<kB, 256, 0, stream>>>(his_mem, null_mem, gumbel_u, (float*)d_out,
                                    empty0, cnt, total, list, listPos, ambBatch,
                                    amb);
    prep2_k<<<2560, 256, 0, stream>>>(attn_W, his_mem, null_mem, states,
                                      global_trace, attn_b, total, ambBatch,
                                      list, C0, qCache, cwCache, stepNz);
    phaseB_k<<<kB, 256, 0, stream>>>(C0, empty0, amb, cnt, listPos, qCache,
                                     cwCache, stepNz, states, states_mask,
                                     gumbel_u, global_trace, attn_W, attn_b, v,
                                     (float*)d_out);
}